// Round 2
// baseline (156.024 us; speedup 1.0000x reference)
//
#include <hip/hip_runtime.h>

// Problem constants
#define M_ROWS 8192            // B*L = 4*2048
#define N_DIM  1024            // D
#define K3     3072            // 3*D
#define KD     16              // K_DIM

typedef __bf16 bf16x8 __attribute__((ext_vector_type(8)));
typedef float  f32x4  __attribute__((ext_vector_type(4)));

__device__ __forceinline__ unsigned short f2bf(float f) {
  return __builtin_bit_cast(unsigned short, (__bf16)f);
}
__device__ __forceinline__ float bf2f(unsigned short u) {
  return __builtin_bit_cast(float, (unsigned int)u << 16);
}

__device__ __forceinline__ void async16(const void* g, void* l) {
  __builtin_amdgcn_global_load_lds(
      (const __attribute__((address_space(1))) unsigned int*)g,
      (__attribute__((address_space(3))) unsigned int*)l, 16, 0, 0);
}

// Kernel 1: convert x,y,z (fp32) -> Xb,Yb,Zb (bf16) AND P = bf16(x*y) (product in fp32).
__global__ __launch_bounds__(256) void convert_kernel(
    const float4* __restrict__ x, const float4* __restrict__ y, const float4* __restrict__ z,
    ushort4* __restrict__ Xb, ushort4* __restrict__ Yb, ushort4* __restrict__ Zb,
    ushort4* __restrict__ P)
{
  int i = blockIdx.x * 256 + threadIdx.x;          // 0 .. 2^21-1 (float4 units)
  float4 fx = x[i], fy = y[i], fz = z[i];
  ushort4 ox, oy, oz, op;
  ox.x = f2bf(fx.x); ox.y = f2bf(fx.y); ox.z = f2bf(fx.z); ox.w = f2bf(fx.w);
  oy.x = f2bf(fy.x); oy.y = f2bf(fy.y); oy.z = f2bf(fy.z); oy.w = f2bf(fy.w);
  oz.x = f2bf(fz.x); oz.y = f2bf(fz.y); oz.z = f2bf(fz.z); oz.w = f2bf(fz.w);
  op.x = f2bf(fx.x * fy.x); op.y = f2bf(fx.y * fy.y);
  op.z = f2bf(fx.z * fy.z); op.w = f2bf(fx.w * fy.w);
  Xb[i] = ox; Yb[i] = oy; Zb[i] = oz; P[i] = op;
}

// Kernel 2: Wsum[d][c] = bf16( sum_{k<16} W[d*16+k][c] ), 1024x3072 row-major.
__global__ __launch_bounds__(256) void reduce_w_kernel(
    const float* __restrict__ W, ushort4* __restrict__ Wsum)
{
  int g  = blockIdx.x * 256 + threadIdx.x;         // 0 .. 786431 (float4 cols)
  int d  = g / 768;                                // 3072/4 = 768 float4 per row
  int cq = g - d * 768;
  const float4* wrow = (const float4*)(W + (size_t)d * (KD * K3));
  float sx = 0.f, sy = 0.f, sz = 0.f, sw = 0.f;
  #pragma unroll
  for (int k = 0; k < KD; ++k) {
    float4 t = wrow[(size_t)k * (K3 / 4) + cq];
    sx += t.x; sy += t.y; sz += t.z; sw += t.w;
  }
  ushort4 o;
  o.x = f2bf(sx); o.y = f2bf(sy); o.z = f2bf(sz); o.w = f2bf(sw);
  Wsum[g] = o;
}

// Kernel 3: bsum[d] = sum_{k<16} b[d*16+k], fp32.
__global__ __launch_bounds__(256) void reduce_b_kernel(
    const float* __restrict__ b, float* __restrict__ bsum)
{
  int d = blockIdx.x * 256 + threadIdx.x;
  if (d < N_DIM) {
    float s = 0.f;
    #pragma unroll
    for (int k = 0; k < KD; ++k) s += b[d * KD + k];
    bsum[d] = s;
  }
}

// Kernel 4: GEMM C[m,n] = sum_k A[m,k]*Wsum[n,k], fused epilogue
//   out[m,n] = (C + bsum[n]) * P[m,n]
// 128x128 tile, BK=64, 4 waves (2x2), 16x16x32 bf16 MFMA, global_load_lds(16B).
__global__ __launch_bounds__(256) void gemm_ep_kernel(
    const unsigned short* __restrict__ Xb, const unsigned short* __restrict__ Yb,
    const unsigned short* __restrict__ Zb, const unsigned short* __restrict__ Wsum,
    const float* __restrict__ bsum, const unsigned short* __restrict__ P,
    float* __restrict__ out)
{
  __shared__ unsigned short sA[128 * 64];   // 16 KB, 128B rows
  __shared__ unsigned short sB[128 * 64];   // 16 KB

  // XCD-aware bijective swizzle: 512 blocks, 8 XCDs, 64 blocks each.
  int bid = blockIdx.x;
  int swz = (bid & 7) * 64 + (bid >> 3);
  int mt = swz >> 3;          // 64 M-tiles
  int nt = swz & 7;           // 8 N-tiles
  int m0 = mt * 128, n0 = nt * 128;

  int tid  = threadIdx.x;
  int lane = tid & 63;
  int wid  = tid >> 6;
  int wr = wid >> 1, wc = wid & 1;   // 2x2 wave grid, each wave 64x64 out

  // staging geometry: 16KB tile = 1024 x 16B; 256 threads -> 4 rounds
  // round r byte offset: o = tid*16 + r*4096; row = o>>7 (128B rows); col same all rounds
  int o0 = tid * 16;
  int colh = (o0 & 127) >> 1;        // column in ushort units
  int row0 = o0 >> 7;                // rows 0..31 (round r adds 32)

  f32x4 acc[4][4];
  #pragma unroll
  for (int i = 0; i < 4; ++i)
    #pragma unroll
    for (int j = 0; j < 4; ++j)
      acc[i][j] = f32x4{0.f, 0.f, 0.f, 0.f};

  int fr = lane & 15;
  int fk = (lane >> 4) << 3;  // k-offset of this lane's 8 bf16

  for (int kt = 0; kt < K3 / 64; ++kt) {   // 48 K-steps
    int kb = kt >> 4;                      // source buffer: 16 steps per 1024 K
    const unsigned short* ab = (kb == 0) ? Xb : ((kb == 1) ? Yb : Zb);
    int ck = (kt & 15) << 6;               // k offset within buffer
    int kw = kt << 6;                      // k offset in Wsum

    #pragma unroll
    for (int r = 0; r < 4; ++r) {
      int row = row0 + r * 32;
      int ob  = o0 + r * 4096;
      async16(ab   + (size_t)(m0 + row) * 1024 + ck + colh, (char*)sA + ob);
      async16(Wsum + (size_t)(n0 + row) * K3   + kw + colh, (char*)sB + ob);
    }
    __syncthreads();   // compiler emits vmcnt(0) drain before barrier

    #pragma unroll
    for (int kk = 0; kk < 2; ++kk) {
      bf16x8 a[4], b[4];
      #pragma unroll
      for (int i = 0; i < 4; ++i)
        a[i] = *(const bf16x8*)&sA[(wr * 64 + i * 16 + fr) * 64 + kk * 32 + fk];
      #pragma unroll
      for (int j = 0; j < 4; ++j)
        b[j] = *(const bf16x8*)&sB[(wc * 64 + j * 16 + fr) * 64 + kk * 32 + fk];

      #pragma unroll
      for (int i = 0; i < 4; ++i)
        #pragma unroll
        for (int j = 0; j < 4; ++j)
          acc[i][j] = __builtin_amdgcn_mfma_f32_16x16x32_bf16(a[i], b[j], acc[i][j], 0, 0, 0);
    }

    __syncthreads();   // protect LDS from next iteration's staging
  }

  // Epilogue: C/D layout col = lane&15, row = (lane>>4)*4 + reg  [verified m89/m91]
  int fq = lane >> 4;
  #pragma unroll
  for (int i = 0; i < 4; ++i) {
    #pragma unroll
    for (int j = 0; j < 4; ++j) {
      int n = n0 + wc * 64 + j * 16 + fr;
      float bs = bsum[n];
      #pragma unroll
      for (int r = 0; r < 4; ++r) {
        int m = m0 + wr * 64 + i * 16 + fq * 4 + r;
        size_t idx = (size_t)m * N_DIM + n;
        out[idx] = (acc[i][j][r] + bs) * bf2f(P[idx]);
      }
    }
  }
}

extern "C" void kernel_launch(void* const* d_in, const int* in_sizes, int n_in,
                              void* d_out, int out_size, void* d_ws, size_t ws_size,
                              hipStream_t stream) {
  const float* x = (const float*)d_in[0];
  const float* y = (const float*)d_in[1];
  const float* z = (const float*)d_in[2];
  const float* W = (const float*)d_in[3];
  const float* b = (const float*)d_in[4];
  float* out = (float*)d_out;

  // ws layout: Xb,Yb,Zb bf16 [8192*1024]; Wsum bf16 [1024*3072]; P bf16 [8192*1024]; bsum f32[1024]
  unsigned short* Xb   = (unsigned short*)d_ws;
  unsigned short* Yb   = Xb + (size_t)M_ROWS * N_DIM;
  unsigned short* Zb   = Yb + (size_t)M_ROWS * N_DIM;
  unsigned short* Wsum = Zb + (size_t)M_ROWS * N_DIM;
  unsigned short* P    = Wsum + (size_t)N_DIM * K3;
  float*          bsum = (float*)(P + (size_t)M_ROWS * N_DIM);

  // 1) convert inputs to bf16 + product: 8192*1024/4 float4 elements
  convert_kernel<<<8192, 256, 0, stream>>>(
      (const float4*)x, (const float4*)y, (const float4*)z,
      (ushort4*)Xb, (ushort4*)Yb, (ushort4*)Zb, (ushort4*)P);

  // 2) reduce W over k: 1024*768 float4 outputs
  reduce_w_kernel<<<3072, 256, 0, stream>>>(W, (ushort4*)Wsum);

  // 3) reduce bias
  reduce_b_kernel<<<4, 256, 0, stream>>>(b, bsum);

  // 4) GEMM + epilogue: 64 x 8 tiles of 128x128
  gemm_ep_kernel<<<512, 256, 0, stream>>>(Xb, Yb, Zb, Wsum, bsum, P, out);
}

// Round 3
// 153.207 us; speedup vs baseline: 1.0184x; 1.0184x over previous
//
#include <hip/hip_runtime.h>

// Problem constants
#define M_ROWS 8192            // B*L = 4*2048
#define N_DIM  1024            // D
#define K3     3072            // 3*D
#define KD     16              // K_DIM
#define NKT    48              // K3 / 64 K-tiles

typedef __bf16 bf16x8 __attribute__((ext_vector_type(8)));
typedef float  f32x4  __attribute__((ext_vector_type(4)));

__device__ __forceinline__ unsigned short f2bf(float f) {
  return __builtin_bit_cast(unsigned short, (__bf16)f);
}
__device__ __forceinline__ float bf2f(unsigned short u) {
  return __builtin_bit_cast(float, (unsigned int)u << 16);
}
__device__ __forceinline__ ushort4 pack4(float4 f) {
  ushort4 o; o.x = f2bf(f.x); o.y = f2bf(f.y); o.z = f2bf(f.z); o.w = f2bf(f.w);
  return o;
}

__device__ __forceinline__ void async16(const void* g, void* l) {
  __builtin_amdgcn_global_load_lds(
      (const __attribute__((address_space(1))) unsigned int*)g,
      (__attribute__((address_space(3))) unsigned int*)l, 16, 0, 0);
}

// Fused prep:
//  blocks [0, 8192):       convert x,y,z -> Ib[8192][3072] bf16 (cols: x|y|z) and P = bf16(x*y)
//  blocks [8192, 11264):   Wsum[d][c] = bf16(sum_k W[d*16+k][c])  (1024x3072)
//  blocks [11264, 11268):  bsum[d] = sum_k b[d*16+k]  (fp32)
__global__ __launch_bounds__(256) void prep_kernel(
    const float4* __restrict__ x, const float4* __restrict__ y, const float4* __restrict__ z,
    const float* __restrict__ W, const float* __restrict__ b,
    ushort4* __restrict__ Ib4, ushort4* __restrict__ P4,
    ushort4* __restrict__ Wsum4, float* __restrict__ bsum)
{
  int bid = blockIdx.x;
  int tid = threadIdx.x;
  if (bid < 8192) {
    int i = bid * 256 + tid;          // float4 index over [8192][256]
    int m = bid;                      // row (i>>8 == bid since tid<256)
    int c4 = tid;                     // float4-col within 1024-col panel
    float4 fx = x[i], fy = y[i], fz = z[i];
    size_t rb = (size_t)m * 768;
    Ib4[rb + c4]       = pack4(fx);
    Ib4[rb + 256 + c4] = pack4(fy);
    Ib4[rb + 512 + c4] = pack4(fz);
    float4 p; p.x = fx.x * fy.x; p.y = fx.y * fy.y; p.z = fx.z * fy.z; p.w = fx.w * fy.w;
    P4[i] = pack4(p);
  } else if (bid < 11264) {
    int g  = (bid - 8192) * 256 + tid;   // 0 .. 786431 float4 cols
    int d  = g / 768;
    int cq = g - d * 768;
    const float4* wrow = (const float4*)(W + (size_t)d * (KD * K3));
    float sx = 0.f, sy = 0.f, sz = 0.f, sw = 0.f;
    #pragma unroll
    for (int k = 0; k < KD; ++k) {
      float4 t = wrow[(size_t)k * (K3 / 4) + cq];
      sx += t.x; sy += t.y; sz += t.z; sw += t.w;
    }
    ushort4 o; o.x = f2bf(sx); o.y = f2bf(sy); o.z = f2bf(sz); o.w = f2bf(sw);
    Wsum4[g] = o;
  } else {
    int d = (bid - 11264) * 256 + tid;
    if (d < N_DIM) {
      float s = 0.f;
      #pragma unroll
      for (int k = 0; k < KD; ++k) s += b[d * KD + k];
      bsum[d] = s;
    }
  }
}

// GEMM C[m,n] = sum_k Ib[m,k]*Wsum[n,k]; out[m,n] = (C + bsum[n]) * P[m,n]
// 128x128 tile, BK=64, dbuf LDS, counted-vmcnt pipeline, XOR chunk swizzle.
__global__ __launch_bounds__(256) void gemm_ep_kernel(
    const unsigned short* __restrict__ Ib, const unsigned short* __restrict__ Wsum,
    const float* __restrict__ bsum, const unsigned short* __restrict__ P,
    float* __restrict__ out)
{
  // LDS: [row][chunk] where chunk = 16B granule (8/row); content of [r][u] is
  // global chunk u^(r&7) of row r.  Linear dest for global_load_lds; swizzle
  // applied on the global SOURCE address and again on the ds_read address.
  __shared__ unsigned short sA[2][128 * 64];   // 16 KB each
  __shared__ unsigned short sB[2][128 * 64];

  // XCD-aware bijective swizzle: 512 blocks, 8 XCDs, 64 blocks each.
  int bid = blockIdx.x;
  int swz = (bid & 7) * 64 + (bid >> 3);
  int mt = swz >> 3;          // 64 M-tiles
  int nt = swz & 7;           // 8 N-tiles
  int m0 = mt * 128, n0 = nt * 128;

  int tid  = threadIdx.x;
  int lane = tid & 63;
  int wid  = tid >> 6;
  int wr = wid >> 1, wc = wid & 1;   // 2x2 wave grid, each wave 64x64 out

  // staging geometry: per tile 16KB A + 16KB B; 256 thr x 16B = 4KB/round -> 4 rounds each
  int o0   = tid * 16;               // byte offset, round r adds r*4096
  int row0 = o0 >> 7;                // rows 0..31 (round adds 32)
  int ch0  = (o0 >> 4) & 7;          // chunk within 128B row (invariant across rounds)

  const unsigned short* Abase = Ib   + (size_t)m0 * K3;
  const unsigned short* Bbase = Wsum + (size_t)n0 * K3;

  f32x4 acc[4][4];
  #pragma unroll
  for (int i = 0; i < 4; ++i)
    #pragma unroll
    for (int j = 0; j < 4; ++j)
      acc[i][j] = f32x4{0.f, 0.f, 0.f, 0.f};

  int fr = lane & 15;
  int hi = lane >> 4;                // 0..3

  // stage K-tile t into buffer s (linear LDS dest, source chunk pre-swizzled)
  auto STAGE = [&](int s, int t) {
    int k0 = t << 6;
    #pragma unroll
    for (int r = 0; r < 4; ++r) {
      int row = row0 + r * 32;
      int sc  = ((ch0 ^ (row & 7)) << 3);          // source chunk start, ushort units
      size_t goff = (size_t)row * K3 + k0 + sc;
      async16(Abase + goff, (char*)sA[s] + o0 + r * 4096);
      async16(Bbase + goff, (char*)sB[s] + o0 + r * 4096);
    }
  };

  STAGE(0, 0);

  for (int t = 0; t < NKT; ++t) {
    int cur = t & 1;
    if (t < NKT - 1) {
      STAGE(cur ^ 1, t + 1);
      // own tile-t loads (8 oldest) done; tile t+1's 8 stay in flight across barrier
      asm volatile("s_waitcnt vmcnt(8)" ::: "memory");
    } else {
      asm volatile("s_waitcnt vmcnt(0)" ::: "memory");
    }
    __builtin_amdgcn_s_barrier();     // tile t fully visible in LDS to all waves

    const unsigned short* pA = sA[cur];
    const unsigned short* pB = sB[cur];
    #pragma unroll
    for (int kk = 0; kk < 2; ++kk) {
      bf16x8 a[4], b[4];
      int c = (kk << 2) + hi;                       // logical chunk 0..7
      #pragma unroll
      for (int i = 0; i < 4; ++i) {
        int R = wr * 64 + i * 16 + fr;
        a[i] = *(const bf16x8*)&pA[(R << 6) + ((c ^ (R & 7)) << 3)];
      }
      #pragma unroll
      for (int j = 0; j < 4; ++j) {
        int R = wc * 64 + j * 16 + fr;
        b[j] = *(const bf16x8*)&pB[(R << 6) + ((c ^ (R & 7)) << 3)];
      }
      #pragma unroll
      for (int i = 0; i < 4; ++i)
        #pragma unroll
        for (int j = 0; j < 4; ++j)
          acc[i][j] = __builtin_amdgcn_mfma_f32_16x16x32_bf16(a[i], b[j], acc[i][j], 0, 0, 0);
    }

    // all of this wave's LDS reads landed in regs; after barrier, buffer is reusable
    asm volatile("s_waitcnt lgkmcnt(0)" ::: "memory");
    __builtin_amdgcn_s_barrier();
  }

  // Epilogue: C/D layout col = lane&15, row = (lane>>4)*4 + reg  [verified m89/m91]
  #pragma unroll
  for (int i = 0; i < 4; ++i) {
    #pragma unroll
    for (int j = 0; j < 4; ++j) {
      int n = n0 + wc * 64 + j * 16 + fr;
      float bs = bsum[n];
      #pragma unroll
      for (int r = 0; r < 4; ++r) {
        int m = m0 + wr * 64 + i * 16 + hi * 4 + r;
        size_t idx = (size_t)m * N_DIM + n;
        out[idx] = (acc[i][j][r] + bs) * bf2f(P[idx]);
      }
    }
  }
}

extern "C" void kernel_launch(void* const* d_in, const int* in_sizes, int n_in,
                              void* d_out, int out_size, void* d_ws, size_t ws_size,
                              hipStream_t stream) {
  const float* x = (const float*)d_in[0];
  const float* y = (const float*)d_in[1];
  const float* z = (const float*)d_in[2];
  const float* W = (const float*)d_in[3];
  const float* b = (const float*)d_in[4];
  float* out = (float*)d_out;

  // ws layout: Ib bf16 [8192*3072]; Wsum bf16 [1024*3072]; P bf16 [8192*1024]; bsum f32[1024]
  unsigned short* Ib   = (unsigned short*)d_ws;
  unsigned short* Wsum = Ib + (size_t)M_ROWS * K3;
  unsigned short* P    = Wsum + (size_t)N_DIM * K3;
  float*          bsum = (float*)(P + (size_t)M_ROWS * N_DIM);

  // 1) fused prep: convert (8192 blocks) + reduce_w (3072) + reduce_b (4)
  prep_kernel<<<11268, 256, 0, stream>>>(
      (const float4*)x, (const float4*)y, (const float4*)z, W, b,
      (ushort4*)Ib, (ushort4*)P, (ushort4*)Wsum, bsum);

  // 2) GEMM + epilogue: 64 x 8 tiles of 128x128
  gemm_ep_kernel<<<512, 256, 0, stream>>>(Ib, Wsum, bsum, P, out);
}

// Round 4
// 140.545 us; speedup vs baseline: 1.1101x; 1.0901x over previous
//
#include <hip/hip_runtime.h>

// Problem constants
#define M_ROWS 8192            // B*L = 4*2048
#define N_DIM  1024            // D
#define K3     3072            // 3*D
#define KD     16              // K_DIM
#define NKT    48              // K3 / BK
#define BM     256
#define BN     128
#define BK     64
#define LDS_A  (BM * BK)       // 16384 ushorts = 32 KB
#define LDS_B  (BN * BK)       // 8192 ushorts  = 16 KB
#define LDS_TILE (LDS_A + LDS_B)  // 24576 ushorts = 48 KB; 3 buffers = 144 KB

typedef __bf16 bf16x8 __attribute__((ext_vector_type(8)));
typedef float  f32x4  __attribute__((ext_vector_type(4)));

__device__ __forceinline__ unsigned short f2bf(float f) {
  return __builtin_bit_cast(unsigned short, (__bf16)f);
}
__device__ __forceinline__ float bf2f(unsigned short u) {
  return __builtin_bit_cast(float, (unsigned int)u << 16);
}
__device__ __forceinline__ ushort4 pack4(float4 f) {
  ushort4 o; o.x = f2bf(f.x); o.y = f2bf(f.y); o.z = f2bf(f.z); o.w = f2bf(f.w);
  return o;
}

__device__ __forceinline__ void async16(const void* g, void* l) {
  __builtin_amdgcn_global_load_lds(
      (const __attribute__((address_space(1))) unsigned int*)g,
      (__attribute__((address_space(3))) unsigned int*)l, 16, 0, 0);
}

// Fused prep:
//  blocks [0, 8192):       convert x,y,z -> Ib[8192][3072] bf16 (cols: x|y|z) and P = bf16(x*y)
//  blocks [8192, 11264):   Wsum[d][c] = bf16(sum_k W[d*16+k][c])  (1024x3072)
//  blocks [11264, 11268):  bsum[d] = sum_k b[d*16+k]  (fp32)
__global__ __launch_bounds__(256) void prep_kernel(
    const float4* __restrict__ x, const float4* __restrict__ y, const float4* __restrict__ z,
    const float* __restrict__ W, const float* __restrict__ b,
    ushort4* __restrict__ Ib4, ushort4* __restrict__ P4,
    ushort4* __restrict__ Wsum4, float* __restrict__ bsum)
{
  int bid = blockIdx.x;
  int tid = threadIdx.x;
  if (bid < 8192) {
    int i = bid * 256 + tid;          // float4 index over [8192][256]
    int m = bid;
    int c4 = tid;
    float4 fx = x[i], fy = y[i], fz = z[i];
    size_t rb = (size_t)m * 768;
    Ib4[rb + c4]       = pack4(fx);
    Ib4[rb + 256 + c4] = pack4(fy);
    Ib4[rb + 512 + c4] = pack4(fz);
    float4 p; p.x = fx.x * fy.x; p.y = fx.y * fy.y; p.z = fx.z * fy.z; p.w = fx.w * fy.w;
    P4[i] = pack4(p);
  } else if (bid < 11264) {
    int g  = (bid - 8192) * 256 + tid;   // 0 .. 786431 float4 cols
    int d  = g / 768;
    int cq = g - d * 768;
    const float4* wrow = (const float4*)(W + (size_t)d * (KD * K3));
    float sx = 0.f, sy = 0.f, sz = 0.f, sw = 0.f;
    #pragma unroll
    for (int k = 0; k < KD; ++k) {
      float4 t = wrow[(size_t)k * (K3 / 4) + cq];
      sx += t.x; sy += t.y; sz += t.z; sw += t.w;
    }
    ushort4 o; o.x = f2bf(sx); o.y = f2bf(sy); o.z = f2bf(sz); o.w = f2bf(sw);
    Wsum4[g] = o;
  } else {
    int d = (bid - 11264) * 256 + tid;
    if (d < N_DIM) {
      float s = 0.f;
      #pragma unroll
      for (int k = 0; k < KD; ++k) s += b[d * KD + k];
      bsum[d] = s;
    }
  }
}

// GEMM C[m,n] = sum_k Ib[m,k]*Wsum[n,k]; out[m,n] = (C + bsum[n]) * P[m,n]
// BM=256 x BN=128 tile, BK=64, 8 waves (4Mx2N), 3-deep LDS pipeline,
// counted vmcnt (12 loads stay in flight across barriers), XOR chunk swizzle.
__global__ __launch_bounds__(512, 2) void gemm_ep_kernel(
    const unsigned short* __restrict__ Ib, const unsigned short* __restrict__ Wsum,
    const float* __restrict__ bsum, const unsigned short* __restrict__ P,
    float* __restrict__ out)
{
  extern __shared__ unsigned short lds[];   // 3 * LDS_TILE ushorts = 144 KB

  // XCD-aware bijective swizzle: 256 blocks, 8 XCDs, 32 blocks each.
  // XCD x covers mt in [4x,4x+4) x all 8 nt -> per-XCD M-band of 1024 rows.
  int bid = blockIdx.x;
  int swz = (bid & 7) * 32 + (bid >> 3);
  int mt = swz >> 3;          // 0..31
  int nt = swz & 7;           // 0..7
  int m0 = mt * BM, n0 = nt * BN;

  int tid  = threadIdx.x;     // 0..511
  int lane = tid & 63;
  int wid  = tid >> 6;        // 0..7
  int wr = wid >> 1, wc = wid & 1;   // 4x2 wave grid, each wave 64x64 out

  // staging geometry: A-tile 32KB = 4 rounds x (512 thr x 16B); B-tile 16KB = 2 rounds
  int row0 = tid >> 3;               // 0..63 (round adds 64)
  int ch0  = tid & 7;                // 16B chunk within 128B row
  int dofs = tid * 16;               // byte offset within an 8KB round

  const unsigned short* Abase = Ib   + (size_t)m0 * K3;
  const unsigned short* Bbase = Wsum + (size_t)n0 * K3;

  f32x4 acc[4][4];
  #pragma unroll
  for (int i = 0; i < 4; ++i)
    #pragma unroll
    for (int j = 0; j < 4; ++j)
      acc[i][j] = f32x4{0.f, 0.f, 0.f, 0.f};

  int fr = lane & 15;
  int hi = lane >> 4;                // 0..3

  // stage K-tile t into buffer s: linear LDS dest, source chunk pre-swizzled
  // LDS[s] content: row r, chunk u holds global chunk u^(r&7) of row r.
  auto STAGE = [&](int s, int t) {
    char* dst = (char*)(lds + s * LDS_TILE);
    int k0 = t << 6;
    #pragma unroll
    for (int r = 0; r < 4; ++r) {    // A: rows row0 + 64r
      int row = row0 + r * 64;
      int sc  = ((ch0 ^ (row0 & 7)) << 3);
      async16(Abase + (size_t)row * K3 + k0 + sc, dst + dofs + r * 8192);
    }
    #pragma unroll
    for (int r = 0; r < 2; ++r) {    // B: rows row0 + 64r
      int row = row0 + r * 64;
      int sc  = ((ch0 ^ (row0 & 7)) << 3);
      async16(Bbase + (size_t)row * K3 + k0 + sc, dst + 2 * LDS_A + dofs + r * 8192);
    }
  };

  STAGE(0, 0);
  STAGE(1, 1);

  for (int t = 0; t < NKT; ++t) {
    int cur = t % 3;
    if (t + 2 < NKT) {
      STAGE((t + 2) % 3, t + 2);
      // tile t's 6 loads are the oldest of 18 outstanding; wait to 12
      asm volatile("s_waitcnt vmcnt(12)" ::: "memory");
    } else if (t + 1 < NKT) {
      asm volatile("s_waitcnt vmcnt(6)" ::: "memory");
    } else {
      asm volatile("s_waitcnt vmcnt(0)" ::: "memory");
    }
    __builtin_amdgcn_s_barrier();     // tile t fully visible in LDS to all waves

    const unsigned short* pA = lds + cur * LDS_TILE;
    const unsigned short* pB = pA + LDS_A;

    __builtin_amdgcn_s_setprio(1);
    #pragma unroll
    for (int kk = 0; kk < 2; ++kk) {
      bf16x8 a[4], b[4];
      int c = (kk << 2) + hi;                       // logical chunk 0..7
      #pragma unroll
      for (int i = 0; i < 4; ++i) {
        int R = wr * 64 + i * 16 + fr;
        a[i] = *(const bf16x8*)&pA[(R << 6) + ((c ^ (R & 7)) << 3)];
      }
      #pragma unroll
      for (int j = 0; j < 4; ++j) {
        int R = wc * 64 + j * 16 + fr;
        b[j] = *(const bf16x8*)&pB[(R << 6) + ((c ^ (R & 7)) << 3)];
      }
      #pragma unroll
      for (int i = 0; i < 4; ++i)
        #pragma unroll
        for (int j = 0; j < 4; ++j)
          acc[i][j] = __builtin_amdgcn_mfma_f32_16x16x32_bf16(a[i], b[j], acc[i][j], 0, 0, 0);
    }
    __builtin_amdgcn_s_setprio(0);

    asm volatile("s_waitcnt lgkmcnt(0)" ::: "memory");
    __builtin_amdgcn_s_barrier();     // all waves done reading tile t's buffer
  }

  // Epilogue: C/D layout col = lane&15, row = (lane>>4)*4 + reg  [verified m89/m91]
  #pragma unroll
  for (int i = 0; i < 4; ++i) {
    #pragma unroll
    for (int j = 0; j < 4; ++j) {
      int n = n0 + wc * 64 + j * 16 + fr;
      float bs = bsum[n];
      #pragma unroll
      for (int r = 0; r < 4; ++r) {
        int m = m0 + wr * 64 + i * 16 + hi * 4 + r;
        size_t idx = (size_t)m * N_DIM + n;
        out[idx] = (acc[i][j][r] + bs) * bf2f(P[idx]);
      }
    }
  }
}

extern "C" void kernel_launch(void* const* d_in, const int* in_sizes, int n_in,
                              void* d_out, int out_size, void* d_ws, size_t ws_size,
                              hipStream_t stream) {
  const float* x = (const float*)d_in[0];
  const float* y = (const float*)d_in[1];
  const float* z = (const float*)d_in[2];
  const float* W = (const float*)d_in[3];
  const float* b = (const float*)d_in[4];
  float* out = (float*)d_out;

  // ws layout: Ib bf16 [8192*3072]; Wsum bf16 [1024*3072]; P bf16 [8192*1024]; bsum f32[1024]
  unsigned short* Ib   = (unsigned short*)d_ws;
  unsigned short* Wsum = Ib + (size_t)M_ROWS * K3;
  unsigned short* P    = Wsum + (size_t)N_DIM * K3;
  float*          bsum = (float*)(P + (size_t)M_ROWS * N_DIM);

  // 1) fused prep: convert (8192 blocks) + reduce_w (3072) + reduce_b (4)
  prep_kernel<<<11268, 256, 0, stream>>>(
      (const float4*)x, (const float4*)y, (const float4*)z, W, b,
      (ushort4*)Ib, (ushort4*)P, (ushort4*)Wsum, bsum);

  // 2) GEMM + epilogue: 32 x 8 tiles of 256x128, 144 KB dynamic LDS
  gemm_ep_kernel<<<256, 512, 3 * LDS_TILE * sizeof(unsigned short), stream>>>(
      Ib, Wsum, bsum, P, out);
}

// Round 5
// 130.443 us; speedup vs baseline: 1.1961x; 1.0774x over previous
//
#include <hip/hip_runtime.h>

// Problem constants
#define M_ROWS 8192            // B*L = 4*2048
#define N_DIM  1024            // D
#define K3     3072            // 3*D
#define KD     16              // K_DIM
#define NKT    48              // K3 / BK
#define BM     256
#define BN     128
#define BK     64
#define LDS_A  (BM * BK)       // 16384 ushorts = 32 KB
#define LDS_B  (BN * BK)       // 8192 ushorts  = 16 KB
#define LDS_TILE (LDS_A + LDS_B)  // 24576 ushorts = 48 KB; 3 buffers = 144 KB

typedef __bf16 bf16x8 __attribute__((ext_vector_type(8)));
typedef float  f32x4  __attribute__((ext_vector_type(4)));

__device__ __forceinline__ unsigned short f2bf(float f) {
  return __builtin_bit_cast(unsigned short, (__bf16)f);
}
__device__ __forceinline__ float bf2f(unsigned short u) {
  return __builtin_bit_cast(float, (unsigned int)u << 16);
}
__device__ __forceinline__ ushort4 pack4(float4 f) {
  ushort4 o; o.x = f2bf(f.x); o.y = f2bf(f.y); o.z = f2bf(f.z); o.w = f2bf(f.w);
  return o;
}

__device__ __forceinline__ void async16(const void* g, void* l) {
  __builtin_amdgcn_global_load_lds(
      (const __attribute__((address_space(1))) unsigned int*)g,
      (__attribute__((address_space(3))) unsigned int*)l, 16, 0, 0);
}

// Fused prep:
//  blocks [0, 8192):       convert x,y,z -> Ib[8192][3072] bf16 (cols: x|y|z) and P = bf16(x*y)
//  blocks [8192, 11264):   Wsum[d][c] = bf16(sum_k W[d*16+k][c])  (1024x3072)
//  blocks [11264, 11268):  bsum[d] = sum_k b[d*16+k]  (fp32)
__global__ __launch_bounds__(256) void prep_kernel(
    const float4* __restrict__ x, const float4* __restrict__ y, const float4* __restrict__ z,
    const float* __restrict__ W, const float* __restrict__ b,
    ushort4* __restrict__ Ib4, ushort4* __restrict__ P4,
    ushort4* __restrict__ Wsum4, float* __restrict__ bsum)
{
  int bid = blockIdx.x;
  int tid = threadIdx.x;
  if (bid < 8192) {
    int i = bid * 256 + tid;          // float4 index over [8192][256]
    int m = bid;
    int c4 = tid;
    float4 fx = x[i], fy = y[i], fz = z[i];
    size_t rb = (size_t)m * 768;
    Ib4[rb + c4]       = pack4(fx);
    Ib4[rb + 256 + c4] = pack4(fy);
    Ib4[rb + 512 + c4] = pack4(fz);
    float4 p; p.x = fx.x * fy.x; p.y = fx.y * fy.y; p.z = fx.z * fy.z; p.w = fx.w * fy.w;
    P4[i] = pack4(p);
  } else if (bid < 11264) {
    int g  = (bid - 8192) * 256 + tid;   // 0 .. 786431 float4 cols
    int d  = g / 768;
    int cq = g - d * 768;
    const float4* wrow = (const float4*)(W + (size_t)d * (KD * K3));
    float sx = 0.f, sy = 0.f, sz = 0.f, sw = 0.f;
    #pragma unroll
    for (int k = 0; k < KD; ++k) {
      float4 t = wrow[(size_t)k * (K3 / 4) + cq];
      sx += t.x; sy += t.y; sz += t.z; sw += t.w;
    }
    ushort4 o; o.x = f2bf(sx); o.y = f2bf(sy); o.z = f2bf(sz); o.w = f2bf(sw);
    Wsum4[g] = o;
  } else {
    int d = (bid - 11264) * 256 + tid;
    if (d < N_DIM) {
      float s = 0.f;
      #pragma unroll
      for (int k = 0; k < KD; ++k) s += b[d * KD + k];
      bsum[d] = s;
    }
  }
}

// GEMM C[m,n] = sum_k Ib[m,k]*Wsum[n,k]; out[m,n] = (C + bsum[n]) * P[m,n]
// BM=256 x BN=128, BK=64, 8 waves (4Mx2N, 64x64 each), 3-deep LDS pipeline,
// 2 phases per K-tile (m201-style interleave), counted vmcnt(6) once per K-tile,
// XOR chunk swizzle (T2), setprio around MFMA cluster (T5).
__global__ __launch_bounds__(512, 2) void gemm_ep_kernel(
    const unsigned short* __restrict__ Ib, const unsigned short* __restrict__ Wsum,
    const float* __restrict__ bsum, const unsigned short* __restrict__ P,
    float* __restrict__ out)
{
  extern __shared__ unsigned short lds[];   // 3 * LDS_TILE ushorts = 144 KB

  // XCD-aware bijective swizzle: 256 blocks, 8 XCDs, 32 blocks each.
  int bid = blockIdx.x;
  int swz = (bid & 7) * 32 + (bid >> 3);
  int mt = swz >> 3;          // 0..31
  int nt = swz & 7;           // 0..7
  int m0 = mt * BM, n0 = nt * BN;

  int tid  = threadIdx.x;     // 0..511
  int lane = tid & 63;
  int wid  = tid >> 6;        // 0..7
  int wr = wid >> 1, wc = wid & 1;   // 4x2 wave grid, each wave 64x64 out

  // staging geometry: A-tile 32KB = 4 rounds x (512 thr x 16B); B-tile 16KB = 2 rounds
  int row0 = tid >> 3;               // 0..63 (round adds 64)
  int ch0  = tid & 7;                // 16B chunk within 128B row
  int dofs = tid * 16;               // byte offset within an 8KB round
  int sc   = ((ch0 ^ (row0 & 7)) << 3);   // pre-swizzled source chunk (ushort units)

  const unsigned short* Abase = Ib   + (size_t)m0 * K3;
  const unsigned short* Bbase = Wsum + (size_t)n0 * K3;

  f32x4 acc[4][4];
  #pragma unroll
  for (int i = 0; i < 4; ++i)
    #pragma unroll
    for (int j = 0; j < 4; ++j)
      acc[i][j] = f32x4{0.f, 0.f, 0.f, 0.f};

  int fr = lane & 15;
  int hi = lane >> 4;                // 0..3

  // stage parts of K-tile t into buffer s: linear LDS dest, source pre-swizzled.
  // LDS[s] content: row r, chunk u holds global chunk u^(r&7) of row r.
  auto STAGE_A = [&](int s, int t, int rlo, int rhi) {
    char* dst = (char*)(lds + s * LDS_TILE);
    int k0 = t << 6;
    for (int r = rlo; r < rhi; ++r)
      async16(Abase + (size_t)(row0 + r * 64) * K3 + k0 + sc, dst + dofs + r * 8192);
  };
  auto STAGE_B = [&](int s, int t, int rlo, int rhi) {
    char* dst = (char*)(lds + s * LDS_TILE) + 2 * LDS_A;   // bytes
    int k0 = t << 6;
    for (int r = rlo; r < rhi; ++r)
      async16(Bbase + (size_t)(row0 + r * 64) * K3 + k0 + sc, dst + dofs + r * 8192);
  };

  bf16x8 a[4], b[4];
  auto LOADAB = [&](const unsigned short* pA, const unsigned short* pB, int kk) {
    int c = (kk << 2) + hi;                 // logical chunk 0..7
    #pragma unroll
    for (int i = 0; i < 4; ++i) {
      int R = wr * 64 + i * 16 + fr;
      a[i] = *(const bf16x8*)&pA[(R << 6) + ((c ^ (R & 7)) << 3)];
    }
    #pragma unroll
    for (int j = 0; j < 4; ++j) {
      int R = wc * 64 + j * 16 + fr;
      b[j] = *(const bf16x8*)&pB[(R << 6) + ((c ^ (R & 7)) << 3)];
    }
  };
  auto MFMA16 = [&]() {
    __builtin_amdgcn_s_setprio(1);
    #pragma unroll
    for (int i = 0; i < 4; ++i)
      #pragma unroll
      for (int j = 0; j < 4; ++j)
        acc[i][j] = __builtin_amdgcn_mfma_f32_16x16x32_bf16(a[i], b[j], acc[i][j], 0, 0, 0);
    __builtin_amdgcn_s_setprio(0);
  };

  // prologue: fill tiles 0 and 1 (6 loads each)
  STAGE_A(0, 0, 0, 4); STAGE_B(0, 0, 0, 2);
  STAGE_A(1, 1, 0, 4); STAGE_B(1, 1, 0, 2);
  asm volatile("s_waitcnt vmcnt(6)" ::: "memory");   // tile 0 landed; tile 1 in flight
  __builtin_amdgcn_s_barrier();

  for (int t = 0; t < NKT; ++t) {
    const unsigned short* pA = lds + (t % 3) * LDS_TILE;
    const unsigned short* pB = pA + LDS_A;
    int s2 = (t + 2) % 3;
    bool st = (t + 2) < NKT;

    // ---- Phase 0 (kk = 0): ds_read || stage A-part || bar || MFMA || bar ----
    LOADAB(pA, pB, 0);
    if (st) STAGE_A(s2, t + 2, 0, 3);
    __builtin_amdgcn_s_barrier();
    asm volatile("s_waitcnt lgkmcnt(0)" ::: "memory");
    __builtin_amdgcn_sched_barrier(0);
    MFMA16();
    __builtin_amdgcn_s_barrier();

    // ---- Phase 1 (kk = 1): ds_read || stage rest || vmcnt || bar || MFMA || bar ----
    LOADAB(pA, pB, 1);
    if (st) { STAGE_A(s2, t + 2, 3, 4); STAGE_B(s2, t + 2, 0, 2); }
    if (st) asm volatile("s_waitcnt vmcnt(6)" ::: "memory");   // tile t+1 landed
    else    asm volatile("s_waitcnt vmcnt(0)" ::: "memory");
    __builtin_amdgcn_s_barrier();
    asm volatile("s_waitcnt lgkmcnt(0)" ::: "memory");
    __builtin_amdgcn_sched_barrier(0);
    MFMA16();
    __builtin_amdgcn_s_barrier();
  }

  // Epilogue: C/D layout col = lane&15, row = (lane>>4)*4 + reg  [verified m89/m91]
  #pragma unroll
  for (int i = 0; i < 4; ++i) {
    #pragma unroll
    for (int j = 0; j < 4; ++j) {
      int n = n0 + wc * 64 + j * 16 + fr;
      float bs = bsum[n];
      #pragma unroll
      for (int r = 0; r < 4; ++r) {
        int m = m0 + wr * 64 + i * 16 + hi * 4 + r;
        size_t idx = (size_t)m * N_DIM + n;
        out[idx] = (acc[i][j][r] + bs) * bf2f(P[idx]);
      }
    }
  }
}

extern "C" void kernel_launch(void* const* d_in, const int* in_sizes, int n_in,
                              void* d_out, int out_size, void* d_ws, size_t ws_size,
                              hipStream_t stream) {
  const float* x = (const float*)d_in[0];
  const float* y = (const float*)d_in[1];
  const float* z = (const float*)d_in[2];
  const float* W = (const float*)d_in[3];
  const float* b = (const float*)d_in[4];
  float* out = (float*)d_out;

  // ws layout: Ib bf16 [8192*3072]; Wsum bf16 [1024*3072]; P bf16 [8192*1024]; bsum f32[1024]
  unsigned short* Ib   = (unsigned short*)d_ws;
  unsigned short* Wsum = Ib + (size_t)M_ROWS * K3;
  unsigned short* P    = Wsum + (size_t)N_DIM * K3;
  float*          bsum = (float*)(P + (size_t)M_ROWS * N_DIM);

  // 1) fused prep: convert (8192 blocks) + reduce_w (3072) + reduce_b (4)
  prep_kernel<<<11268, 256, 0, stream>>>(
      (const float4*)x, (const float4*)y, (const float4*)z, W, b,
      (ushort4*)Ib, (ushort4*)P, (ushort4*)Wsum, bsum);

  // 2) GEMM + epilogue: 32 x 8 tiles of 256x128, 144 KB dynamic LDS
  gemm_ep_kernel<<<256, 512, 3 * LDS_TILE * sizeof(unsigned short), stream>>>(
      Ib, Wsum, bsum, P, out);
}